// Round 1
// baseline (1180.496 us; speedup 1.0000x reference)
//
#include <hip/hip_runtime.h>
#include <hip/hip_bf16.h>
#include <math.h>

#define N_NODES 100000
#define N_EDGES 1600000
#define D 128

// ---- workspace layout (bytes) ----
#define OFF_SSRC 0                    // int[E]      sorted src ids   (6,400,000)
#define OFF_OFFS 6400000              // int[N+1]    CSR offsets      (400,004 -> pad)
#define OFF_CURS 6800016              // int[N]      counts/cursors   (400,000)
#define OFF_BSUM 7200016              // int[1024]   scan block sums
#define OFF_A    7204112              // float[N*D]
#define OFF_B    58404112             // float[N*D]  (total ~109.6 MB)

// ---------------- edge bucket sort ----------------
__global__ void count_kernel(const int* __restrict__ dst, int* __restrict__ cnt) {
    int e = blockIdx.x * blockDim.x + threadIdx.x;
    atomicAdd(&cnt[dst[e]], 1);
}

__global__ void scan_a(const int* __restrict__ cnt, int* __restrict__ offs,
                       int* __restrict__ bsum) {
    __shared__ int sh[256];
    int t = threadIdx.x;
    int i = blockIdx.x * 256 + t;
    int v = (i < N_NODES) ? cnt[i] : 0;
    sh[t] = v;
    __syncthreads();
    for (int off = 1; off < 256; off <<= 1) {
        int y = (t >= off) ? sh[t - off] : 0;
        __syncthreads();
        sh[t] += y;
        __syncthreads();
    }
    if (i < N_NODES) offs[i] = sh[t] - v;          // block-local exclusive
    if (t == 255) bsum[blockIdx.x] = sh[255];
}

__global__ void scan_b(int* __restrict__ bsum, int nb) {
    __shared__ int sh[512];
    int t = threadIdx.x;
    int v = (t < nb) ? bsum[t] : 0;
    sh[t] = v;
    __syncthreads();
    for (int off = 1; off < 512; off <<= 1) {
        int y = (t >= off) ? sh[t - off] : 0;
        __syncthreads();
        sh[t] += y;
        __syncthreads();
    }
    if (t < nb) bsum[t] = sh[t] - v;               // exclusive block prefix
}

__global__ void scan_c(int* __restrict__ offs, const int* __restrict__ bsum,
                       int* __restrict__ curs) {
    int i = blockIdx.x * 256 + threadIdx.x;
    if (i < N_NODES) {
        int o = offs[i] + bsum[blockIdx.x];
        offs[i] = o;
        curs[i] = o;
    }
    if (i == 0) offs[N_NODES] = N_EDGES;
}

__global__ void fill_kernel(const int* __restrict__ src, const int* __restrict__ dst,
                            int* __restrict__ curs, int* __restrict__ s_src) {
    int e = blockIdx.x * blockDim.x + threadIdx.x;
    int pos = atomicAdd(&curs[dst[e]], 1);
    s_src[pos] = src[e];
}

// ---------------- mean aggregation ----------------
__global__ __launch_bounds__(128) void agg_kernel(const float* __restrict__ h,
                                                  const int* __restrict__ s_src,
                                                  const int* __restrict__ offs,
                                                  float* __restrict__ mean) {
    int node = blockIdx.x;
    int t = threadIdx.x;
    int beg = offs[node], end = offs[node + 1];
    float acc = 0.f;
    int e = beg;
    for (; e + 1 < end; e += 2) {
        int s0 = s_src[e], s1 = s_src[e + 1];
        float v0 = h[s0 * D + t];
        float v1 = h[s1 * D + t];
        acc += v0 + v1;
    }
    if (e < end) acc += h[s_src[e] * D + t];
    float c = (float)(end - beg);
    mean[node * D + t] = acc / fmaxf(c, 1.0f);
}

// ---------------- fused linear: out = mean@Wl + bl + h@Wr ----------------
// 128 threads, 32 nodes/block, each thread computes 4 nodes x 8 channels.
// tile row padded +4 floats -> 4-row broadcast ds_read_b128 hits distinct banks.
#define TM 32
#define TPAD 4
__global__ __launch_bounds__(128) void mm_kernel(const float* __restrict__ h,
                                                 const float* mean,  // may alias out
                                                 const float* __restrict__ Wl,
                                                 const float* __restrict__ Wr,
                                                 const float* __restrict__ bl,
                                                 float* out) {
    __shared__ float tile[TM][256 + TPAD];
    int t = threadIdx.x;
    int bn = blockIdx.x * TM;

    // stage [mean | h] tile: 32 nodes x 256 cols, float4 loads
    for (int i = 0; i < 16; ++i) {
        int idx = i * 128 + t;              // float4 index, 0..2047
        int m = idx >> 6;                   // 64 float4 per row
        int k4 = idx & 63;
        int node = bn + m;
        float4 v;
        if (k4 < 32) v = ((const float4*)mean)[node * 32 + k4];
        else         v = ((const float4*)h)[node * 32 + (k4 - 32)];
        *(float4*)&tile[m][k4 * 4] = v;
    }
    __syncthreads();

    int mg = t >> 4, jg = t & 15;
    int m0 = mg * 4, j0 = jg * 8;
    float acc[4][8];
#pragma unroll
    for (int i = 0; i < 4; ++i)
#pragma unroll
        for (int j = 0; j < 8; ++j) acc[i][j] = 0.f;

#pragma unroll
    for (int half = 0; half < 2; ++half) {
        const float* Wp = half ? Wr : Wl;
        const int ko = half * 128;
        for (int k = 0; k < 128; k += 4) {
            float a[4][4];
#pragma unroll
            for (int i = 0; i < 4; ++i)
                *(float4*)&a[i][0] = *(const float4*)&tile[m0 + i][ko + k];
#pragma unroll
            for (int r = 0; r < 4; ++r) {
                float4 w0 = *(const float4*)&Wp[(k + r) * D + j0];
                float4 w1 = *(const float4*)&Wp[(k + r) * D + j0 + 4];
#pragma unroll
                for (int i = 0; i < 4; ++i) {
                    float av = a[i][r];
                    acc[i][0] = fmaf(av, w0.x, acc[i][0]);
                    acc[i][1] = fmaf(av, w0.y, acc[i][1]);
                    acc[i][2] = fmaf(av, w0.z, acc[i][2]);
                    acc[i][3] = fmaf(av, w0.w, acc[i][3]);
                    acc[i][4] = fmaf(av, w1.x, acc[i][4]);
                    acc[i][5] = fmaf(av, w1.y, acc[i][5]);
                    acc[i][6] = fmaf(av, w1.z, acc[i][6]);
                    acc[i][7] = fmaf(av, w1.w, acc[i][7]);
                }
            }
        }
    }

    float4 bb0 = *(const float4*)&bl[j0];
    float4 bb1 = *(const float4*)&bl[j0 + 4];
#pragma unroll
    for (int i = 0; i < 4; ++i) {
        int node = bn + m0 + i;
        float4 o0 = make_float4(acc[i][0] + bb0.x, acc[i][1] + bb0.y,
                                acc[i][2] + bb0.z, acc[i][3] + bb0.w);
        float4 o1 = make_float4(acc[i][4] + bb1.x, acc[i][5] + bb1.y,
                                acc[i][6] + bb1.z, acc[i][7] + bb1.w);
        *(float4*)&out[node * D + j0] = o0;
        *(float4*)&out[node * D + j0 + 4] = o1;
    }
}

// ---------------- LayerNorm (+ELU | +L2 normalize), in place ----------------
__global__ __launch_bounds__(256) void ln_kernel(float* __restrict__ io,
                                                 const float* __restrict__ g,
                                                 const float* __restrict__ b,
                                                 int last) {
    int wid = threadIdx.x >> 6;
    int lane = threadIdx.x & 63;
    int node = blockIdx.x * 4 + wid;
    float2 v = *(float2*)&io[node * D + lane * 2];
    float s = v.x + v.y;
#pragma unroll
    for (int off = 32; off; off >>= 1) s += __shfl_xor(s, off);
    float mu = s * (1.0f / 128.0f);
    float dx0 = v.x - mu, dx1 = v.y - mu;
    float q = dx0 * dx0 + dx1 * dx1;
#pragma unroll
    for (int off = 32; off; off >>= 1) q += __shfl_xor(q, off);
    float rstd = rsqrtf(q * (1.0f / 128.0f) + 1e-5f);
    float2 gg = *(const float2*)&g[lane * 2];
    float2 bb = *(const float2*)&b[lane * 2];
    float y0 = dx0 * rstd * gg.x + bb.x;
    float y1 = dx1 * rstd * gg.y + bb.y;
    if (!last) {
        y0 = (y0 > 0.f) ? y0 : expm1f(y0);
        y1 = (y1 > 0.f) ? y1 : expm1f(y1);
    } else {
        float ss = y0 * y0 + y1 * y1;
#pragma unroll
        for (int off = 32; off; off >>= 1) ss += __shfl_xor(ss, off);
        float inv = 1.0f / fmaxf(sqrtf(ss), 1e-12f);
        y0 *= inv;
        y1 *= inv;
    }
    *(float2*)&io[node * D + lane * 2] = make_float2(y0, y1);
}

extern "C" void kernel_launch(void* const* d_in, const int* in_sizes, int n_in,
                              void* d_out, int out_size, void* d_ws, size_t ws_size,
                              hipStream_t stream) {
    const float* x = (const float*)d_in[0];
    const int* edges = (const int*)d_in[1];
    const int* src = edges;
    const int* dst = edges + N_EDGES;
    const float* Wl[3] = {(const float*)d_in[2], (const float*)d_in[7],  (const float*)d_in[12]};
    const float* bl[3] = {(const float*)d_in[3], (const float*)d_in[8],  (const float*)d_in[13]};
    const float* Wr[3] = {(const float*)d_in[4], (const float*)d_in[9],  (const float*)d_in[14]};
    const float* g[3]  = {(const float*)d_in[5], (const float*)d_in[10], (const float*)d_in[15]};
    const float* b[3]  = {(const float*)d_in[6], (const float*)d_in[11], (const float*)d_in[16]};

    char* ws = (char*)d_ws;
    int* s_src = (int*)(ws + OFF_SSRC);
    int* offs  = (int*)(ws + OFF_OFFS);
    int* curs  = (int*)(ws + OFF_CURS);
    int* bsum  = (int*)(ws + OFF_BSUM);
    float* A   = (float*)(ws + OFF_A);
    float* B   = (float*)(ws + OFF_B);
    float* out = (float*)d_out;

    // ---- bucket-sort edges by dst (once; reused by all 3 layers) ----
    hipMemsetAsync(curs, 0, N_NODES * sizeof(int), stream);
    count_kernel<<<N_EDGES / 256, 256, 0, stream>>>(dst, curs);
    int nb = (N_NODES + 255) / 256;  // 391
    scan_a<<<nb, 256, 0, stream>>>(curs, offs, bsum);
    scan_b<<<1, 512, 0, stream>>>(bsum, nb);
    scan_c<<<nb, 256, 0, stream>>>(offs, bsum, curs);
    fill_kernel<<<N_EDGES / 256, 256, 0, stream>>>(src, dst, curs, s_src);

    // ---- layer 0: h = x -> A ----
    agg_kernel<<<N_NODES, 128, 0, stream>>>(x, s_src, offs, A);
    mm_kernel<<<N_NODES / TM, 128, 0, stream>>>(x, A, Wl[0], Wr[0], bl[0], A);
    ln_kernel<<<N_NODES / 4, 256, 0, stream>>>(A, g[0], b[0], 0);
    // ---- layer 1: h = A -> B ----
    agg_kernel<<<N_NODES, 128, 0, stream>>>(A, s_src, offs, B);
    mm_kernel<<<N_NODES / TM, 128, 0, stream>>>(A, B, Wl[1], Wr[1], bl[1], B);
    ln_kernel<<<N_NODES / 4, 256, 0, stream>>>(B, g[1], b[1], 0);
    // ---- layer 2: h = B -> d_out (+ final L2 normalize) ----
    agg_kernel<<<N_NODES, 128, 0, stream>>>(B, s_src, offs, A);
    mm_kernel<<<N_NODES / TM, 128, 0, stream>>>(B, A, Wl[2], Wr[2], bl[2], out);
    ln_kernel<<<N_NODES / 4, 256, 0, stream>>>(out, g[2], b[2], 1);
}

// Round 2
// 903.576 us; speedup vs baseline: 1.3065x; 1.3065x over previous
//
#include <hip/hip_runtime.h>
#include <hip/hip_bf16.h>
#include <math.h>

#define N_NODES 100000
#define N_EDGES 1600000
#define D 128

// ---- workspace layout (bytes) ----
#define OFF_SSRC 0                    // int[E]      sorted src ids   (6,400,000)
#define OFF_OFFS 6400000              // int[N+1]    CSR offsets
#define OFF_CURS 6800016              // int[N] counts/cursors; REUSED as W_pack (393,216 B) after sort
#define OFF_BSUM 7200016              // int[1024]   scan block sums
#define OFF_A    7204112              // float[N*D]
#define OFF_B    58404112             // float[N*D]

typedef __attribute__((ext_vector_type(8))) short short8;
typedef __attribute__((ext_vector_type(4))) float floatx4;

__device__ __forceinline__ unsigned short f2bf(float f) {
    unsigned int u = __float_as_uint(f);
    u += 0x7fffu + ((u >> 16) & 1u);   // RNE
    return (unsigned short)(u >> 16);
}
__device__ __forceinline__ float bf2f(unsigned short h) {
    return __uint_as_float(((unsigned int)h) << 16);
}

// ---------------- edge bucket sort ----------------
__global__ void count_kernel(const int* __restrict__ dst, int* __restrict__ cnt) {
    int e = blockIdx.x * blockDim.x + threadIdx.x;
    atomicAdd(&cnt[dst[e]], 1);
}

__global__ void scan_a(const int* __restrict__ cnt, int* __restrict__ offs,
                       int* __restrict__ bsum) {
    __shared__ int sh[256];
    int t = threadIdx.x;
    int i = blockIdx.x * 256 + t;
    int v = (i < N_NODES) ? cnt[i] : 0;
    sh[t] = v;
    __syncthreads();
    for (int off = 1; off < 256; off <<= 1) {
        int y = (t >= off) ? sh[t - off] : 0;
        __syncthreads();
        sh[t] += y;
        __syncthreads();
    }
    if (i < N_NODES) offs[i] = sh[t] - v;
    if (t == 255) bsum[blockIdx.x] = sh[255];
}

__global__ void scan_b(int* __restrict__ bsum, int nb) {
    __shared__ int sh[512];
    int t = threadIdx.x;
    int v = (t < nb) ? bsum[t] : 0;
    sh[t] = v;
    __syncthreads();
    for (int off = 1; off < 512; off <<= 1) {
        int y = (t >= off) ? sh[t - off] : 0;
        __syncthreads();
        sh[t] += y;
        __syncthreads();
    }
    if (t < nb) bsum[t] = sh[t] - v;
}

__global__ void scan_c(int* __restrict__ offs, const int* __restrict__ bsum,
                       int* __restrict__ curs) {
    int i = blockIdx.x * 256 + threadIdx.x;
    if (i < N_NODES) {
        int o = offs[i] + bsum[blockIdx.x];
        offs[i] = o;
        curs[i] = o;
    }
    if (i == 0) offs[N_NODES] = N_EDGES;
}

__global__ void fill_kernel(const int* __restrict__ src, const int* __restrict__ dst,
                            int* __restrict__ curs, int* __restrict__ s_src) {
    int e = blockIdx.x * blockDim.x + threadIdx.x;
    int pos = atomicAdd(&curs[dst[e]], 1);
    s_src[pos] = src[e];
}

// ---------------- weight pack: fragment-ordered bf16 hi/lo ----------------
// pack layout per layer: [hi 32768 | lo 32768] ushort.
// fragment elem (ct,ks,lane,j) <-> B[k=ks*32+(lane>>4)*8+j][n=ct*16+(lane&15)]
__global__ void pack_kernel(const float* __restrict__ Wl0, const float* __restrict__ Wr0,
                            const float* __restrict__ Wl1, const float* __restrict__ Wr1,
                            const float* __restrict__ Wl2, const float* __restrict__ Wr2,
                            unsigned short* __restrict__ pack) {
    int tid = blockIdx.x * blockDim.x + threadIdx.x;   // 3*32768 threads
    int l = tid >> 15;
    int r = tid & 32767;
    int k = r >> 7;
    int n = r & 127;
    const float* Wl = (l == 0) ? Wl0 : (l == 1) ? Wl1 : Wl2;
    const float* Wr = (l == 0) ? Wr0 : (l == 1) ? Wr1 : Wr2;
    float v = (k < 128) ? Wl[k * 128 + n] : Wr[(k - 128) * 128 + n];
    unsigned short hi = f2bf(v);
    unsigned short lo = f2bf(v - bf2f(hi));
    int ct = n >> 4, ks = k >> 5, lane = ((k >> 3) & 3) * 16 + (n & 15), j = k & 7;
    int idx = ((ct * 8 + ks) * 64 + lane) * 8 + j;
    pack[l * 65536 + idx] = hi;
    pack[l * 65536 + 32768 + idx] = lo;
}

// ---------------- mean aggregation ----------------
__global__ __launch_bounds__(128) void agg_kernel(const float* __restrict__ h,
                                                  const int* __restrict__ s_src,
                                                  const int* __restrict__ offs,
                                                  float* __restrict__ mean) {
    int node = blockIdx.x;
    int t = threadIdx.x;
    int beg = offs[node], end = offs[node + 1];
    float acc = 0.f;
    int e = beg;
    for (; e + 1 < end; e += 2) {
        int s0 = s_src[e], s1 = s_src[e + 1];
        float v0 = h[s0 * D + t];
        float v1 = h[s1 * D + t];
        acc += v0 + v1;
    }
    if (e < end) acc += h[s_src[e] * D + t];
    float c = (float)(end - beg);
    mean[node * D + t] = acc / fmaxf(c, 1.0f);
}

// ---------------- fused MFMA linear + LN(+ELU | +L2norm) ----------------
// out = LN(mean@Wl + bl + h@Wr) [+ELU | +L2normalize]
// 256 threads = 4 waves; wave computes 32 rows x 128 cols via split-bf16 MFMA.
__global__ __launch_bounds__(256) void mmln_kernel(const float* __restrict__ h,
                                                   const float* mean,   // may alias out
                                                   const unsigned short* __restrict__ packh,
                                                   const unsigned short* __restrict__ packl,
                                                   const float* __restrict__ bl,
                                                   const float* __restrict__ g,
                                                   const float* __restrict__ b,
                                                   float* out, int last) {
    int t = threadIdx.x;
    int lane = t & 63;
    int wid = t >> 6;
    int colb = lane & 15;
    int quad = lane >> 4;
    int kq = quad * 8;
    int tilebase = blockIdx.x * 128 + wid * 32;

    int rowA[2];
    rowA[0] = min(tilebase + colb, N_NODES - 1);
    rowA[1] = min(tilebase + 16 + colb, N_NODES - 1);

    floatx4 acc[2][8];
#pragma unroll
    for (int rt = 0; rt < 2; ++rt)
#pragma unroll
        for (int ct = 0; ct < 8; ++ct) acc[rt][ct] = (floatx4){0.f, 0.f, 0.f, 0.f};

#pragma unroll
    for (int ks = 0; ks < 8; ++ks) {
        const float* sb = (ks < 4) ? mean : h;
        int kof = (ks & 3) * 32 + kq;
        short8 ah[2], al[2];
#pragma unroll
        for (int rt = 0; rt < 2; ++rt) {
            const float* p = sb + (long)rowA[rt] * D + kof;
            float4 v0 = *(const float4*)p;
            float4 v1 = *(const float4*)(p + 4);
            float v[8] = {v0.x, v0.y, v0.z, v0.w, v1.x, v1.y, v1.z, v1.w};
#pragma unroll
            for (int j = 0; j < 8; ++j) {
                unsigned short hi = f2bf(v[j]);
                ah[rt][j] = (short)hi;
                al[rt][j] = (short)f2bf(v[j] - bf2f(hi));
            }
        }
#pragma unroll
        for (int ct = 0; ct < 8; ++ct) {
            int fo = ((ct * 8 + ks) << 9) + (lane << 3);
            short8 bh = *(const short8*)(packh + fo);
            short8 bo = *(const short8*)(packl + fo);
#pragma unroll
            for (int rt = 0; rt < 2; ++rt) {
                acc[rt][ct] = __builtin_amdgcn_mfma_f32_16x16x32_bf16(ah[rt], bh, acc[rt][ct], 0, 0, 0);
                acc[rt][ct] = __builtin_amdgcn_mfma_f32_16x16x32_bf16(al[rt], bh, acc[rt][ct], 0, 0, 0);
                acc[rt][ct] = __builtin_amdgcn_mfma_f32_16x16x32_bf16(ah[rt], bo, acc[rt][ct], 0, 0, 0);
            }
        }
    }

    // per-column params (col = ct*16 + colb)
    float bb[8], gg[8], b2[8];
#pragma unroll
    for (int ct = 0; ct < 8; ++ct) {
        bb[ct] = bl[ct * 16 + colb];
        gg[ct] = g[ct * 16 + colb];
        b2[ct] = b[ct * 16 + colb];
    }

#pragma unroll
    for (int rt = 0; rt < 2; ++rt) {
        // bias
#pragma unroll
        for (int ct = 0; ct < 8; ++ct)
#pragma unroll
            for (int e = 0; e < 4; ++e) acc[rt][ct][e] += bb[ct];
        // LN stats per row (row = tilebase + rt*16 + quad*4 + e); a full row
        // lives in one 16-lane quad -> shfl_xor 1,2,4,8 stays in-quad.
        float mu[4], rstd[4];
#pragma unroll
        for (int e = 0; e < 4; ++e) {
            float s = 0.f;
#pragma unroll
            for (int ct = 0; ct < 8; ++ct) s += acc[rt][ct][e];
            s += __shfl_xor(s, 1); s += __shfl_xor(s, 2);
            s += __shfl_xor(s, 4); s += __shfl_xor(s, 8);
            mu[e] = s * (1.0f / 128.0f);
        }
#pragma unroll
        for (int e = 0; e < 4; ++e) {
            float q = 0.f;
#pragma unroll
            for (int ct = 0; ct < 8; ++ct) {
                float d = acc[rt][ct][e] - mu[e];
                q += d * d;
            }
            q += __shfl_xor(q, 1); q += __shfl_xor(q, 2);
            q += __shfl_xor(q, 4); q += __shfl_xor(q, 8);
            rstd[e] = rsqrtf(q * (1.0f / 128.0f) + 1e-5f);
        }
#pragma unroll
        for (int ct = 0; ct < 8; ++ct)
#pragma unroll
            for (int e = 0; e < 4; ++e) {
                float y = (acc[rt][ct][e] - mu[e]) * rstd[e] * gg[ct] + b2[ct];
                if (!last) y = (y > 0.f) ? y : expm1f(y);
                acc[rt][ct][e] = y;
            }
        if (last) {
#pragma unroll
            for (int e = 0; e < 4; ++e) {
                float ss = 0.f;
#pragma unroll
                for (int ct = 0; ct < 8; ++ct) {
                    float y = acc[rt][ct][e];
                    ss += y * y;
                }
                ss += __shfl_xor(ss, 1); ss += __shfl_xor(ss, 2);
                ss += __shfl_xor(ss, 4); ss += __shfl_xor(ss, 8);
                float inv = 1.0f / fmaxf(sqrtf(ss), 1e-12f);
#pragma unroll
                for (int ct = 0; ct < 8; ++ct) acc[rt][ct][e] *= inv;
            }
        }
        // store (4B per lane; 4 rows x 16-col segments per instr)
#pragma unroll
        for (int e = 0; e < 4; ++e) {
            int row = tilebase + rt * 16 + quad * 4 + e;
            if (row < N_NODES) {
#pragma unroll
                for (int ct = 0; ct < 8; ++ct)
                    out[(long)row * D + ct * 16 + colb] = acc[rt][ct][e];
            }
        }
    }
}

extern "C" void kernel_launch(void* const* d_in, const int* in_sizes, int n_in,
                              void* d_out, int out_size, void* d_ws, size_t ws_size,
                              hipStream_t stream) {
    const float* x = (const float*)d_in[0];
    const int* edges = (const int*)d_in[1];
    const int* src = edges;
    const int* dst = edges + N_EDGES;
    const float* Wl[3] = {(const float*)d_in[2], (const float*)d_in[7],  (const float*)d_in[12]};
    const float* bl[3] = {(const float*)d_in[3], (const float*)d_in[8],  (const float*)d_in[13]};
    const float* Wr[3] = {(const float*)d_in[4], (const float*)d_in[9],  (const float*)d_in[14]};
    const float* g[3]  = {(const float*)d_in[5], (const float*)d_in[10], (const float*)d_in[15]};
    const float* b[3]  = {(const float*)d_in[6], (const float*)d_in[11], (const float*)d_in[16]};

    char* ws = (char*)d_ws;
    int* s_src = (int*)(ws + OFF_SSRC);
    int* offs  = (int*)(ws + OFF_OFFS);
    int* curs  = (int*)(ws + OFF_CURS);
    int* bsum  = (int*)(ws + OFF_BSUM);
    unsigned short* wpack = (unsigned short*)(ws + OFF_CURS);  // reuse after sort
    float* A   = (float*)(ws + OFF_A);
    float* B   = (float*)(ws + OFF_B);
    float* out = (float*)d_out;

    // ---- bucket-sort edges by dst (reused by all 3 layers) ----
    hipMemsetAsync(curs, 0, N_NODES * sizeof(int), stream);
    count_kernel<<<N_EDGES / 256, 256, 0, stream>>>(dst, curs);
    int nb = (N_NODES + 255) / 256;  // 391
    scan_a<<<nb, 256, 0, stream>>>(curs, offs, bsum);
    scan_b<<<1, 512, 0, stream>>>(bsum, nb);
    scan_c<<<nb, 256, 0, stream>>>(offs, bsum, curs);
    fill_kernel<<<N_EDGES / 256, 256, 0, stream>>>(src, dst, curs, s_src);
    // curs region is now dead -> pack weights there (bf16 hi/lo fragments)
    pack_kernel<<<(3 * 32768) / 256, 256, 0, stream>>>(Wl[0], Wr[0], Wl[1], Wr[1], Wl[2], Wr[2], wpack);

    const int MMB = (N_NODES + 127) / 128;  // 782
    unsigned short* ph[3] = {wpack, wpack + 65536, wpack + 131072};
    // ---- layer 0 ----
    agg_kernel<<<N_NODES, 128, 0, stream>>>(x, s_src, offs, A);
    mmln_kernel<<<MMB, 256, 0, stream>>>(x, A, ph[0], ph[0] + 32768, bl[0], g[0], b[0], A, 0);
    // ---- layer 1 ----
    agg_kernel<<<N_NODES, 128, 0, stream>>>(A, s_src, offs, B);
    mmln_kernel<<<MMB, 256, 0, stream>>>(A, B, ph[1], ph[1] + 32768, bl[1], g[1], b[1], B, 0);
    // ---- layer 2 ----
    agg_kernel<<<N_NODES, 128, 0, stream>>>(B, s_src, offs, A);
    mmln_kernel<<<MMB, 256, 0, stream>>>(B, A, ph[2], ph[2] + 32768, bl[2], g[2], b[2], out, 1);
}

// Round 3
// 779.388 us; speedup vs baseline: 1.5146x; 1.1593x over previous
//
#include <hip/hip_runtime.h>
#include <hip/hip_bf16.h>
#include <math.h>

#define N_NODES 100000
#define N_EDGES 1600000
#define D 128

// ---- workspace layout (bytes), total 109,604,112 ----
#define OFF_SSRC 0                    // int[E]      sorted src ids   (6,400,000)
#define OFF_OFFS 6400000              // int[N+1]    CSR offsets
#define OFF_CURS 6800016              // int[N] counts/cursors; REUSED as W_pack (393,216 B) after sort
#define OFF_BSUM 7200016              // int[1024]   scan block sums
#define OFF_M    7204112              // float[N*D]   mean buffer (51.2 MB)
#define OFF_XHI  58404112             // ushort[N*D]  h hi plane (25.6 MB)
#define OFF_XLO  84004112             // ushort[N*D]  h lo plane (25.6 MB)

typedef __attribute__((ext_vector_type(8))) short short8;
typedef __attribute__((ext_vector_type(4))) float floatx4;

__device__ __forceinline__ unsigned short f2bf(float f) {
    unsigned int u = __float_as_uint(f);
    u += 0x7fffu + ((u >> 16) & 1u);   // RNE
    return (unsigned short)(u >> 16);
}
__device__ __forceinline__ float bf2f(unsigned short h) {
    return __uint_as_float(((unsigned int)h) << 16);
}

// ---------------- edge bucket sort ----------------
__global__ void count_kernel(const int* __restrict__ dst, int* __restrict__ cnt) {
    int e = blockIdx.x * blockDim.x + threadIdx.x;
    atomicAdd(&cnt[dst[e]], 1);
}

__global__ void scan_a(const int* __restrict__ cnt, int* __restrict__ offs,
                       int* __restrict__ bsum) {
    __shared__ int sh[256];
    int t = threadIdx.x;
    int i = blockIdx.x * 256 + t;
    int v = (i < N_NODES) ? cnt[i] : 0;
    sh[t] = v;
    __syncthreads();
    for (int off = 1; off < 256; off <<= 1) {
        int y = (t >= off) ? sh[t - off] : 0;
        __syncthreads();
        sh[t] += y;
        __syncthreads();
    }
    if (i < N_NODES) offs[i] = sh[t] - v;
    if (t == 255) bsum[blockIdx.x] = sh[255];
}

__global__ void scan_b(int* __restrict__ bsum, int nb) {
    __shared__ int sh[512];
    int t = threadIdx.x;
    int v = (t < nb) ? bsum[t] : 0;
    sh[t] = v;
    __syncthreads();
    for (int off = 1; off < 512; off <<= 1) {
        int y = (t >= off) ? sh[t - off] : 0;
        __syncthreads();
        sh[t] += y;
        __syncthreads();
    }
    if (t < nb) bsum[t] = sh[t] - v;
}

__global__ void scan_c(int* __restrict__ offs, const int* __restrict__ bsum,
                       int* __restrict__ curs) {
    int i = blockIdx.x * 256 + threadIdx.x;
    if (i < N_NODES) {
        int o = offs[i] + bsum[blockIdx.x];
        offs[i] = o;
        curs[i] = o;
    }
    if (i == 0) offs[N_NODES] = N_EDGES;
}

__global__ void fill_kernel(const int* __restrict__ src, const int* __restrict__ dst,
                            int* __restrict__ curs, int* __restrict__ s_src) {
    int e = blockIdx.x * blockDim.x + threadIdx.x;
    int pos = atomicAdd(&curs[dst[e]], 1);
    s_src[pos] = src[e];
}

// ---------------- weight pack: fragment-ordered bf16 hi/lo ----------------
// pack layout per layer: [hi 32768 | lo 32768] ushort.
// fragment elem (ct,ks,lane,j) <-> B[k=ks*32+(lane>>4)*8+j][n=ct*16+(lane&15)]
__global__ void pack_kernel(const float* __restrict__ Wl0, const float* __restrict__ Wr0,
                            const float* __restrict__ Wl1, const float* __restrict__ Wr1,
                            const float* __restrict__ Wl2, const float* __restrict__ Wr2,
                            unsigned short* __restrict__ pack) {
    int tid = blockIdx.x * blockDim.x + threadIdx.x;   // 3*32768 threads
    int l = tid >> 15;
    int r = tid & 32767;
    int k = r >> 7;
    int n = r & 127;
    const float* Wl = (l == 0) ? Wl0 : (l == 1) ? Wl1 : Wl2;
    const float* Wr = (l == 0) ? Wr0 : (l == 1) ? Wr1 : Wr2;
    float v = (k < 128) ? Wl[k * 128 + n] : Wr[(k - 128) * 128 + n];
    unsigned short hi = f2bf(v);
    unsigned short lo = f2bf(v - bf2f(hi));
    int ct = n >> 4, ks = k >> 5, lane = ((k >> 3) & 3) * 16 + (n & 15), j = k & 7;
    int idx = ((ct * 8 + ks) * 64 + lane) * 8 + j;
    pack[l * 65536 + idx] = hi;
    pack[l * 65536 + 32768 + idx] = lo;
}

// ---------------- fp32 x -> bf16 hi/lo planes ----------------
__global__ __launch_bounds__(256) void cvt_kernel(const float* __restrict__ x,
                                                  unsigned int* __restrict__ Xhi,
                                                  unsigned int* __restrict__ Xlo) {
    int i = blockIdx.x * 256 + threadIdx.x;      // N*64 uints, 2 channels each
    float2 v = ((const float2*)x)[i];
    unsigned short h0 = f2bf(v.x), h1 = f2bf(v.y);
    unsigned short l0 = f2bf(v.x - bf2f(h0)), l1 = f2bf(v.y - bf2f(h1));
    Xhi[i] = (unsigned int)h0 | ((unsigned int)h1 << 16);
    Xlo[i] = (unsigned int)l0 | ((unsigned int)l1 << 16);
}

// ---------------- mean aggregation (bf16-hi gather, wave per node) ----------------
__global__ __launch_bounds__(256) void agg_kernel(const unsigned int* __restrict__ Xhi,
                                                  const int* __restrict__ s_src,
                                                  const int* __restrict__ offs,
                                                  float* __restrict__ mean) {
    int wid = threadIdx.x >> 6, lane = threadIdx.x & 63;
    int node = blockIdx.x * 4 + wid;
    int beg = offs[node], end = offs[node + 1];
    float a0 = 0.f, a1 = 0.f, b0 = 0.f, b1 = 0.f;
    int e = beg;
    for (; e + 3 < end; e += 4) {
        int s0 = s_src[e], s1 = s_src[e + 1], s2 = s_src[e + 2], s3 = s_src[e + 3];
        unsigned int u0 = Xhi[s0 * 64 + lane];
        unsigned int u1 = Xhi[s1 * 64 + lane];
        unsigned int u2 = Xhi[s2 * 64 + lane];
        unsigned int u3 = Xhi[s3 * 64 + lane];
        a0 += bf2f((unsigned short)u0) + bf2f((unsigned short)u1);
        a1 += bf2f((unsigned short)(u0 >> 16)) + bf2f((unsigned short)(u1 >> 16));
        b0 += bf2f((unsigned short)u2) + bf2f((unsigned short)u3);
        b1 += bf2f((unsigned short)(u2 >> 16)) + bf2f((unsigned short)(u3 >> 16));
    }
    for (; e < end; ++e) {
        unsigned int u = Xhi[s_src[e] * 64 + lane];
        a0 += bf2f((unsigned short)u);
        a1 += bf2f((unsigned short)(u >> 16));
    }
    float inv = 1.0f / fmaxf((float)(end - beg), 1.0f);
    ((float2*)mean)[node * 64 + lane] = make_float2((a0 + b0) * inv, (a1 + b1) * inv);
}

// ---------------- fused MFMA linear + LN(+ELU | +L2norm) ----------------
// out = LN(mean@Wl + bl + h@Wr) [+ELU -> store bf16 hi/lo planes in-place |
//                                +L2normalize -> store fp32 to outf]
// h comes in as bf16 hi/lo planes (exactly the split-bf16 operands).
// In-place is safe: each wave reads only its own 32 rows, writes them after.
__global__ __launch_bounds__(256) void mmln_kernel(unsigned short* Xh,  // in/out hi plane
                                                   unsigned short* Xl,  // in/out lo plane
                                                   const float* __restrict__ mean,
                                                   const unsigned short* __restrict__ packh,
                                                   const unsigned short* __restrict__ packl,
                                                   const float* __restrict__ bl,
                                                   const float* __restrict__ g,
                                                   const float* __restrict__ b,
                                                   float* __restrict__ outf, int last) {
    int t = threadIdx.x;
    int lane = t & 63;
    int wid = t >> 6;
    int colb = lane & 15;
    int quad = lane >> 4;
    int kq = quad * 8;
    int tilebase = blockIdx.x * 128 + wid * 32;

    int rowA[2];
    rowA[0] = min(tilebase + colb, N_NODES - 1);
    rowA[1] = min(tilebase + 16 + colb, N_NODES - 1);

    floatx4 acc[2][8];
#pragma unroll
    for (int rt = 0; rt < 2; ++rt)
#pragma unroll
        for (int ct = 0; ct < 8; ++ct) acc[rt][ct] = (floatx4){0.f, 0.f, 0.f, 0.f};

    // ---- ks 0..3: mean @ Wl (fp32 mean -> split hi/lo in-register) ----
#pragma unroll
    for (int ks = 0; ks < 4; ++ks) {
        int kof = ks * 32 + kq;
        short8 ah[2], al[2];
#pragma unroll
        for (int rt = 0; rt < 2; ++rt) {
            const float* p = mean + (long)rowA[rt] * D + kof;
            float4 v0 = *(const float4*)p;
            float4 v1 = *(const float4*)(p + 4);
            float v[8] = {v0.x, v0.y, v0.z, v0.w, v1.x, v1.y, v1.z, v1.w};
#pragma unroll
            for (int j = 0; j < 8; ++j) {
                unsigned short hi = f2bf(v[j]);
                ah[rt][j] = (short)hi;
                al[rt][j] = (short)f2bf(v[j] - bf2f(hi));
            }
        }
#pragma unroll
        for (int ct = 0; ct < 8; ++ct) {
            int fo = ((ct * 8 + ks) << 9) + (lane << 3);
            short8 bh = *(const short8*)(packh + fo);
            short8 bo = *(const short8*)(packl + fo);
#pragma unroll
            for (int rt = 0; rt < 2; ++rt) {
                acc[rt][ct] = __builtin_amdgcn_mfma_f32_16x16x32_bf16(ah[rt], bh, acc[rt][ct], 0, 0, 0);
                acc[rt][ct] = __builtin_amdgcn_mfma_f32_16x16x32_bf16(al[rt], bh, acc[rt][ct], 0, 0, 0);
                acc[rt][ct] = __builtin_amdgcn_mfma_f32_16x16x32_bf16(ah[rt], bo, acc[rt][ct], 0, 0, 0);
            }
        }
    }
    // ---- ks 4..7: h @ Wr (hi/lo planes loaded directly as fragments) ----
#pragma unroll
    for (int ks = 4; ks < 8; ++ks) {
        int kof = (ks - 4) * 32 + kq;
        short8 ah[2], al[2];
#pragma unroll
        for (int rt = 0; rt < 2; ++rt) {
            long o = (long)rowA[rt] * D + kof;
            ah[rt] = *(const short8*)(Xh + o);
            al[rt] = *(const short8*)(Xl + o);
        }
#pragma unroll
        for (int ct = 0; ct < 8; ++ct) {
            int fo = ((ct * 8 + ks) << 9) + (lane << 3);
            short8 bh = *(const short8*)(packh + fo);
            short8 bo = *(const short8*)(packl + fo);
#pragma unroll
            for (int rt = 0; rt < 2; ++rt) {
                acc[rt][ct] = __builtin_amdgcn_mfma_f32_16x16x32_bf16(ah[rt], bh, acc[rt][ct], 0, 0, 0);
                acc[rt][ct] = __builtin_amdgcn_mfma_f32_16x16x32_bf16(al[rt], bh, acc[rt][ct], 0, 0, 0);
                acc[rt][ct] = __builtin_amdgcn_mfma_f32_16x16x32_bf16(ah[rt], bo, acc[rt][ct], 0, 0, 0);
            }
        }
    }

    // per-column params (col = ct*16 + colb)
    float bb[8], gg[8], b2[8];
#pragma unroll
    for (int ct = 0; ct < 8; ++ct) {
        bb[ct] = bl[ct * 16 + colb];
        gg[ct] = g[ct * 16 + colb];
        b2[ct] = b[ct * 16 + colb];
    }

#pragma unroll
    for (int rt = 0; rt < 2; ++rt) {
#pragma unroll
        for (int ct = 0; ct < 8; ++ct)
#pragma unroll
            for (int e = 0; e < 4; ++e) acc[rt][ct][e] += bb[ct];
        // LN stats: full row lives in one 16-lane quad -> shfl_xor 1,2,4,8
        float mu[4], rstd[4];
#pragma unroll
        for (int e = 0; e < 4; ++e) {
            float s = 0.f;
#pragma unroll
            for (int ct = 0; ct < 8; ++ct) s += acc[rt][ct][e];
            s += __shfl_xor(s, 1); s += __shfl_xor(s, 2);
            s += __shfl_xor(s, 4); s += __shfl_xor(s, 8);
            mu[e] = s * (1.0f / 128.0f);
        }
#pragma unroll
        for (int e = 0; e < 4; ++e) {
            float q = 0.f;
#pragma unroll
            for (int ct = 0; ct < 8; ++ct) {
                float d = acc[rt][ct][e] - mu[e];
                q += d * d;
            }
            q += __shfl_xor(q, 1); q += __shfl_xor(q, 2);
            q += __shfl_xor(q, 4); q += __shfl_xor(q, 8);
            rstd[e] = rsqrtf(q * (1.0f / 128.0f) + 1e-5f);
        }
#pragma unroll
        for (int ct = 0; ct < 8; ++ct)
#pragma unroll
            for (int e = 0; e < 4; ++e) {
                float y = (acc[rt][ct][e] - mu[e]) * rstd[e] * gg[ct] + b2[ct];
                if (!last) y = (y > 0.f) ? y : expm1f(y);
                acc[rt][ct][e] = y;
            }
        if (last) {
#pragma unroll
            for (int e = 0; e < 4; ++e) {
                float ss = 0.f;
#pragma unroll
                for (int ct = 0; ct < 8; ++ct) {
                    float y = acc[rt][ct][e];
                    ss += y * y;
                }
                ss += __shfl_xor(ss, 1); ss += __shfl_xor(ss, 2);
                ss += __shfl_xor(ss, 4); ss += __shfl_xor(ss, 8);
                float inv = 1.0f / fmaxf(sqrtf(ss), 1e-12f);
#pragma unroll
                for (int ct = 0; ct < 8; ++ct) acc[rt][ct][e] *= inv;
            }
#pragma unroll
            for (int e = 0; e < 4; ++e) {
                int row = tilebase + rt * 16 + quad * 4 + e;
                if (row < N_NODES) {
#pragma unroll
                    for (int ct = 0; ct < 8; ++ct)
                        outf[(long)row * D + ct * 16 + colb] = acc[rt][ct][e];
                }
            }
        } else {
#pragma unroll
            for (int e = 0; e < 4; ++e) {
                int row = tilebase + rt * 16 + quad * 4 + e;
                if (row < N_NODES) {
#pragma unroll
                    for (int ct = 0; ct < 8; ++ct) {
                        float y = acc[rt][ct][e];
                        unsigned short hh = f2bf(y);
                        unsigned short ll = f2bf(y - bf2f(hh));
                        long o = (long)row * D + ct * 16 + colb;
                        Xh[o] = hh;
                        Xl[o] = ll;
                    }
                }
            }
        }
    }
}

extern "C" void kernel_launch(void* const* d_in, const int* in_sizes, int n_in,
                              void* d_out, int out_size, void* d_ws, size_t ws_size,
                              hipStream_t stream) {
    const float* x = (const float*)d_in[0];
    const int* edges = (const int*)d_in[1];
    const int* src = edges;
    const int* dst = edges + N_EDGES;
    const float* Wl[3] = {(const float*)d_in[2], (const float*)d_in[7],  (const float*)d_in[12]};
    const float* bl[3] = {(const float*)d_in[3], (const float*)d_in[8],  (const float*)d_in[13]};
    const float* Wr[3] = {(const float*)d_in[4], (const float*)d_in[9],  (const float*)d_in[14]};
    const float* g[3]  = {(const float*)d_in[5], (const float*)d_in[10], (const float*)d_in[15]};
    const float* b[3]  = {(const float*)d_in[6], (const float*)d_in[11], (const float*)d_in[16]};

    char* ws = (char*)d_ws;
    int* s_src = (int*)(ws + OFF_SSRC);
    int* offs  = (int*)(ws + OFF_OFFS);
    int* curs  = (int*)(ws + OFF_CURS);
    int* bsum  = (int*)(ws + OFF_BSUM);
    unsigned short* wpack = (unsigned short*)(ws + OFF_CURS);  // reuse after sort
    float* M = (float*)(ws + OFF_M);
    unsigned short* Xhi = (unsigned short*)(ws + OFF_XHI);
    unsigned short* Xlo = (unsigned short*)(ws + OFF_XLO);
    float* out = (float*)d_out;

    // ---- bucket-sort edges by dst (reused by all 3 layers) ----
    hipMemsetAsync(curs, 0, N_NODES * sizeof(int), stream);
    count_kernel<<<N_EDGES / 256, 256, 0, stream>>>(dst, curs);
    int nb = (N_NODES + 255) / 256;  // 391
    scan_a<<<nb, 256, 0, stream>>>(curs, offs, bsum);
    scan_b<<<1, 512, 0, stream>>>(bsum, nb);
    scan_c<<<nb, 256, 0, stream>>>(offs, bsum, curs);
    fill_kernel<<<N_EDGES / 256, 256, 0, stream>>>(src, dst, curs, s_src);
    // curs region now dead -> pack weights there (bf16 hi/lo fragments)
    pack_kernel<<<(3 * 32768) / 256, 256, 0, stream>>>(Wl[0], Wr[0], Wl[1], Wr[1], Wl[2], Wr[2], wpack);
    // x -> bf16 hi/lo planes
    cvt_kernel<<<(N_NODES * 64) / 256, 256, 0, stream>>>(x, (unsigned int*)Xhi, (unsigned int*)Xlo);

    const int MMB = (N_NODES + 127) / 128;  // 782
    unsigned short* ph[3] = {wpack, wpack + 65536, wpack + 131072};

    // ---- layer 0 ----
    agg_kernel<<<N_NODES / 4, 256, 0, stream>>>((const unsigned int*)Xhi, s_src, offs, M);
    mmln_kernel<<<MMB, 256, 0, stream>>>(Xhi, Xlo, M, ph[0], ph[0] + 32768, bl[0], g[0], b[0], nullptr, 0);
    // ---- layer 1 ----
    agg_kernel<<<N_NODES / 4, 256, 0, stream>>>((const unsigned int*)Xhi, s_src, offs, M);
    mmln_kernel<<<MMB, 256, 0, stream>>>(Xhi, Xlo, M, ph[1], ph[1] + 32768, bl[1], g[1], b[1], nullptr, 0);
    // ---- layer 2 ----
    agg_kernel<<<N_NODES / 4, 256, 0, stream>>>((const unsigned int*)Xhi, s_src, offs, M);
    mmln_kernel<<<MMB, 256, 0, stream>>>(Xhi, Xlo, M, ph[2], ph[2] + 32768, bl[2], g[2], b[2], out, 1);
}

// Round 4
// 647.712 us; speedup vs baseline: 1.8226x; 1.2033x over previous
//
#include <hip/hip_runtime.h>
#include <hip/hip_bf16.h>
#include <math.h>

#define N_NODES 100000
#define N_EDGES 1600000
#define D 128
#define NB 391          // buckets = ceil(N/256), bucket = dst >> 8
#define BSTRIDE 6000    // staging cap/bucket (avg 4092, sigma 64 -> 14 sigma headroom)

// ---- workspace layout (bytes), total 109,604,112 ----
#define OFF_SSRC 0                    // int[E]      sorted src ids   (6,400,000)
#define OFF_OFFS 6400000              // int[N+1]    CSR offsets
#define OFF_CURS 6800016              // W_pack (393,216 B)
#define OFF_BSUM 7200016              // gcur[NB] @ +0, bbase[NB] @ +2048
#define OFF_M    7204112              // float[N*D] mean (51.2 MB); staging (18.8 MB) aliases it pre-agg
#define OFF_XHI  58404112             // ushort[N*D]  h hi plane (25.6 MB)
#define OFF_XLO  84004112             // ushort[N*D]  h lo plane (25.6 MB)

typedef __attribute__((ext_vector_type(8))) short short8;
typedef __attribute__((ext_vector_type(4))) float floatx4;

__device__ __forceinline__ unsigned short f2bf(float f) {
    unsigned int u = __float_as_uint(f);
    u += 0x7fffu + ((u >> 16) & 1u);   // RNE
    return (unsigned short)(u >> 16);
}
__device__ __forceinline__ float bf2f(unsigned short h) {
    return __uint_as_float(((unsigned int)h) << 16);
}

// ---------------- pass 1: partition edges into 391 coarse buckets ----------------
__global__ __launch_bounds__(256) void part_kernel(const int* __restrict__ src,
                                                   const int* __restrict__ dst,
                                                   int* __restrict__ gcur,
                                                   uint2* __restrict__ staging) {
    __shared__ int hist[NB];
    __shared__ int base[NB];
    int t = threadIdx.x;
    int e0 = blockIdx.x * 4096;
    for (int i = t; i < NB; i += 256) hist[i] = 0;
    __syncthreads();
    int d[16];
#pragma unroll
    for (int i = 0; i < 16; ++i) {
        int e = e0 + i * 256 + t;
        d[i] = (e < N_EDGES) ? dst[e] : -1;
        if (d[i] >= 0) atomicAdd(&hist[d[i] >> 8], 1);
    }
    __syncthreads();
    for (int i = t; i < NB; i += 256) {
        int h = hist[i];
        base[i] = h ? atomicAdd(&gcur[i], h) : 0;
    }
    __syncthreads();
    for (int i = t; i < NB; i += 256) hist[i] = 0;   // reuse as local cursor
    __syncthreads();
#pragma unroll
    for (int i = 0; i < 16; ++i) {
        if (d[i] >= 0) {
            int e = e0 + i * 256 + t;
            int b = d[i] >> 8;
            int slot = atomicAdd(&hist[b], 1);
            staging[b * BSTRIDE + base[b] + slot] =
                make_uint2((unsigned)src[e], (unsigned)(d[i] & 255));
        }
    }
}

// ---------------- exclusive scan of bucket totals ----------------
__global__ void bscan_kernel(const int* __restrict__ gcur, int* __restrict__ bbase,
                             int* __restrict__ offs) {
    __shared__ int sh[512];
    int t = threadIdx.x;
    int v = (t < NB) ? gcur[t] : 0;
    sh[t] = v;
    __syncthreads();
    for (int off = 1; off < 512; off <<= 1) {
        int y = (t >= off) ? sh[t - off] : 0;
        __syncthreads();
        sh[t] += y;
        __syncthreads();
    }
    if (t < NB) bbase[t] = sh[t] - v;
    if (t == 0) offs[N_NODES] = N_EDGES;
}

// ---------------- pass 2: sort each bucket in LDS, emit CSR ----------------
__global__ __launch_bounds__(256) void bsort_kernel(const uint2* __restrict__ staging,
                                                    const int* __restrict__ gcur,
                                                    const int* __restrict__ bbase,
                                                    int* __restrict__ offs,
                                                    int* __restrict__ s_src) {
    __shared__ int cnt[256];
    __shared__ int scn[256];
    __shared__ int ssrc[BSTRIDE];
    int b = blockIdx.x;
    int t = threadIdx.x;
    int n = gcur[b];
    int base_out = bbase[b];
    cnt[t] = 0;
    __syncthreads();
    for (int e = t; e < n; e += 256) {
        uint2 v = staging[b * BSTRIDE + e];
        atomicAdd(&cnt[v.y], 1);
    }
    __syncthreads();
    int v = cnt[t];
    scn[t] = v;
    __syncthreads();
    for (int off = 1; off < 256; off <<= 1) {
        int y = (t >= off) ? scn[t - off] : 0;
        __syncthreads();
        scn[t] += y;
        __syncthreads();
    }
    int ex = scn[t] - v;                 // exclusive prefix
    int node = b * 256 + t;
    if (node < N_NODES) offs[node] = base_out + ex;
    cnt[t] = ex;                         // reuse as cursor
    __syncthreads();
    for (int e = t; e < n; e += 256) {
        uint2 w = staging[b * BSTRIDE + e];
        int slot = atomicAdd(&cnt[w.y], 1);
        ssrc[slot] = (int)w.x;
    }
    __syncthreads();
    for (int e = t; e < n; e += 256) s_src[base_out + e] = ssrc[e];
}

// ---------------- weight pack: fragment-ordered bf16 hi/lo ----------------
__global__ void pack_kernel(const float* __restrict__ Wl0, const float* __restrict__ Wr0,
                            const float* __restrict__ Wl1, const float* __restrict__ Wr1,
                            const float* __restrict__ Wl2, const float* __restrict__ Wr2,
                            unsigned short* __restrict__ pack) {
    int tid = blockIdx.x * blockDim.x + threadIdx.x;   // 3*32768 threads
    int l = tid >> 15;
    int r = tid & 32767;
    int k = r >> 7;
    int n = r & 127;
    const float* Wl = (l == 0) ? Wl0 : (l == 1) ? Wl1 : Wl2;
    const float* Wr = (l == 0) ? Wr0 : (l == 1) ? Wr1 : Wr2;
    float v = (k < 128) ? Wl[k * 128 + n] : Wr[(k - 128) * 128 + n];
    unsigned short hi = f2bf(v);
    unsigned short lo = f2bf(v - bf2f(hi));
    int ct = n >> 4, ks = k >> 5, lane = ((k >> 3) & 3) * 16 + (n & 15), j = k & 7;
    int idx = ((ct * 8 + ks) * 64 + lane) * 8 + j;
    pack[l * 65536 + idx] = hi;
    pack[l * 65536 + 32768 + idx] = lo;
}

// ---------------- fp32 x -> bf16 hi/lo planes ----------------
__global__ __launch_bounds__(256) void cvt_kernel(const float* __restrict__ x,
                                                  unsigned int* __restrict__ Xhi,
                                                  unsigned int* __restrict__ Xlo) {
    int i = blockIdx.x * 256 + threadIdx.x;      // N*64 uints, 2 channels each
    float2 v = ((const float2*)x)[i];
    unsigned short h0 = f2bf(v.x), h1 = f2bf(v.y);
    unsigned short l0 = f2bf(v.x - bf2f(h0)), l1 = f2bf(v.y - bf2f(h1));
    Xhi[i] = (unsigned int)h0 | ((unsigned int)h1 << 16);
    Xlo[i] = (unsigned int)l0 | ((unsigned int)l1 << 16);
}

// ---------------- mean aggregation (bf16-hi gather, wave per node) ----------------
__global__ __launch_bounds__(256) void agg_kernel(const unsigned int* __restrict__ Xhi,
                                                  const int* __restrict__ s_src,
                                                  const int* __restrict__ offs,
                                                  float* __restrict__ mean) {
    int wid = threadIdx.x >> 6, lane = threadIdx.x & 63;
    int node = blockIdx.x * 4 + wid;
    int beg = offs[node], end = offs[node + 1];
    float a0 = 0.f, a1 = 0.f, b0 = 0.f, b1 = 0.f;
    int e = beg;
    for (; e + 3 < end; e += 4) {
        int s0 = s_src[e], s1 = s_src[e + 1], s2 = s_src[e + 2], s3 = s_src[e + 3];
        unsigned int u0 = Xhi[s0 * 64 + lane];
        unsigned int u1 = Xhi[s1 * 64 + lane];
        unsigned int u2 = Xhi[s2 * 64 + lane];
        unsigned int u3 = Xhi[s3 * 64 + lane];
        a0 += bf2f((unsigned short)u0) + bf2f((unsigned short)u1);
        a1 += bf2f((unsigned short)(u0 >> 16)) + bf2f((unsigned short)(u1 >> 16));
        b0 += bf2f((unsigned short)u2) + bf2f((unsigned short)u3);
        b1 += bf2f((unsigned short)(u2 >> 16)) + bf2f((unsigned short)(u3 >> 16));
    }
    for (; e < end; ++e) {
        unsigned int u = Xhi[s_src[e] * 64 + lane];
        a0 += bf2f((unsigned short)u);
        a1 += bf2f((unsigned short)(u >> 16));
    }
    float inv = 1.0f / fmaxf((float)(end - beg), 1.0f);
    ((float2*)mean)[node * 64 + lane] = make_float2((a0 + b0) * inv, (a1 + b1) * inv);
}

// ---------------- fused MFMA linear + LN(+ELU | +L2norm) ----------------
__global__ __launch_bounds__(256) void mmln_kernel(unsigned short* Xh,  // in/out hi plane
                                                   unsigned short* Xl,  // in/out lo plane
                                                   const float* __restrict__ mean,
                                                   const unsigned short* __restrict__ packh,
                                                   const unsigned short* __restrict__ packl,
                                                   const float* __restrict__ bl,
                                                   const float* __restrict__ g,
                                                   const float* __restrict__ b,
                                                   float* __restrict__ outf, int last) {
    int t = threadIdx.x;
    int lane = t & 63;
    int wid = t >> 6;
    int colb = lane & 15;
    int quad = lane >> 4;
    int kq = quad * 8;
    int tilebase = blockIdx.x * 128 + wid * 32;

    int rowA[2];
    rowA[0] = min(tilebase + colb, N_NODES - 1);
    rowA[1] = min(tilebase + 16 + colb, N_NODES - 1);

    floatx4 acc[2][8];
#pragma unroll
    for (int rt = 0; rt < 2; ++rt)
#pragma unroll
        for (int ct = 0; ct < 8; ++ct) acc[rt][ct] = (floatx4){0.f, 0.f, 0.f, 0.f};

    // ---- ks 0..3: mean @ Wl (fp32 mean -> split hi/lo in-register) ----
#pragma unroll
    for (int ks = 0; ks < 4; ++ks) {
        int kof = ks * 32 + kq;
        short8 ah[2], al[2];
#pragma unroll
        for (int rt = 0; rt < 2; ++rt) {
            const float* p = mean + (long)rowA[rt] * D + kof;
            float4 v0 = *(const float4*)p;
            float4 v1 = *(const float4*)(p + 4);
            float v[8] = {v0.x, v0.y, v0.z, v0.w, v1.x, v1.y, v1.z, v1.w};
#pragma unroll
            for (int j = 0; j < 8; ++j) {
                unsigned short hi = f2bf(v[j]);
                ah[rt][j] = (short)hi;
                al[rt][j] = (short)f2bf(v[j] - bf2f(hi));
            }
        }
#pragma unroll
        for (int ct = 0; ct < 8; ++ct) {
            int fo = ((ct * 8 + ks) << 9) + (lane << 3);
            short8 bh = *(const short8*)(packh + fo);
            short8 bo = *(const short8*)(packl + fo);
#pragma unroll
            for (int rt = 0; rt < 2; ++rt) {
                acc[rt][ct] = __builtin_amdgcn_mfma_f32_16x16x32_bf16(ah[rt], bh, acc[rt][ct], 0, 0, 0);
                acc[rt][ct] = __builtin_amdgcn_mfma_f32_16x16x32_bf16(al[rt], bh, acc[rt][ct], 0, 0, 0);
                acc[rt][ct] = __builtin_amdgcn_mfma_f32_16x16x32_bf16(ah[rt], bo, acc[rt][ct], 0, 0, 0);
            }
        }
    }
    // ---- ks 4..7: h @ Wr (hi/lo planes loaded directly as fragments) ----
#pragma unroll
    for (int ks = 4; ks < 8; ++ks) {
        int kof = (ks - 4) * 32 + kq;
        short8 ah[2], al[2];
#pragma unroll
        for (int rt = 0; rt < 2; ++rt) {
            long o = (long)rowA[rt] * D + kof;
            ah[rt] = *(const short8*)(Xh + o);
            al[rt] = *(const short8*)(Xl + o);
        }
#pragma unroll
        for (int ct = 0; ct < 8; ++ct) {
            int fo = ((ct * 8 + ks) << 9) + (lane << 3);
            short8 bh = *(const short8*)(packh + fo);
            short8 bo = *(const short8*)(packl + fo);
#pragma unroll
            for (int rt = 0; rt < 2; ++rt) {
                acc[rt][ct] = __builtin_amdgcn_mfma_f32_16x16x32_bf16(ah[rt], bh, acc[rt][ct], 0, 0, 0);
                acc[rt][ct] = __builtin_amdgcn_mfma_f32_16x16x32_bf16(al[rt], bh, acc[rt][ct], 0, 0, 0);
                acc[rt][ct] = __builtin_amdgcn_mfma_f32_16x16x32_bf16(ah[rt], bo, acc[rt][ct], 0, 0, 0);
            }
        }
    }

    float bb[8], gg[8], b2[8];
#pragma unroll
    for (int ct = 0; ct < 8; ++ct) {
        bb[ct] = bl[ct * 16 + colb];
        gg[ct] = g[ct * 16 + colb];
        b2[ct] = b[ct * 16 + colb];
    }

#pragma unroll
    for (int rt = 0; rt < 2; ++rt) {
#pragma unroll
        for (int ct = 0; ct < 8; ++ct)
#pragma unroll
            for (int e = 0; e < 4; ++e) acc[rt][ct][e] += bb[ct];
        float mu[4], rstd[4];
#pragma unroll
        for (int e = 0; e < 4; ++e) {
            float s = 0.f;
#pragma unroll
            for (int ct = 0; ct < 8; ++ct) s += acc[rt][ct][e];
            s += __shfl_xor(s, 1); s += __shfl_xor(s, 2);
            s += __shfl_xor(s, 4); s += __shfl_xor(s, 8);
            mu[e] = s * (1.0f / 128.0f);
        }
#pragma unroll
        for (int e = 0; e < 4; ++e) {
            float q = 0.f;
#pragma unroll
            for (int ct = 0; ct < 8; ++ct) {
                float d = acc[rt][ct][e] - mu[e];
                q += d * d;
            }
            q += __shfl_xor(q, 1); q += __shfl_xor(q, 2);
            q += __shfl_xor(q, 4); q += __shfl_xor(q, 8);
            rstd[e] = rsqrtf(q * (1.0f / 128.0f) + 1e-5f);
        }
#pragma unroll
        for (int ct = 0; ct < 8; ++ct)
#pragma unroll
            for (int e = 0; e < 4; ++e) {
                float y = (acc[rt][ct][e] - mu[e]) * rstd[e] * gg[ct] + b2[ct];
                if (!last) y = (y > 0.f) ? y : expm1f(y);
                acc[rt][ct][e] = y;
            }
        if (last) {
#pragma unroll
            for (int e = 0; e < 4; ++e) {
                float ss = 0.f;
#pragma unroll
                for (int ct = 0; ct < 8; ++ct) {
                    float y = acc[rt][ct][e];
                    ss += y * y;
                }
                ss += __shfl_xor(ss, 1); ss += __shfl_xor(ss, 2);
                ss += __shfl_xor(ss, 4); ss += __shfl_xor(ss, 8);
                float inv = 1.0f / fmaxf(sqrtf(ss), 1e-12f);
#pragma unroll
                for (int ct = 0; ct < 8; ++ct) acc[rt][ct][e] *= inv;
            }
#pragma unroll
            for (int e = 0; e < 4; ++e) {
                int row = tilebase + rt * 16 + quad * 4 + e;
                if (row < N_NODES) {
#pragma unroll
                    for (int ct = 0; ct < 8; ++ct)
                        outf[(long)row * D + ct * 16 + colb] = acc[rt][ct][e];
                }
            }
        } else {
#pragma unroll
            for (int e = 0; e < 4; ++e) {
                int row = tilebase + rt * 16 + quad * 4 + e;
                if (row < N_NODES) {
#pragma unroll
                    for (int ct = 0; ct < 8; ++ct) {
                        float y = acc[rt][ct][e];
                        unsigned short hh = f2bf(y);
                        unsigned short ll = f2bf(y - bf2f(hh));
                        long o = (long)row * D + ct * 16 + colb;
                        Xh[o] = hh;
                        Xl[o] = ll;
                    }
                }
            }
        }
    }
}

extern "C" void kernel_launch(void* const* d_in, const int* in_sizes, int n_in,
                              void* d_out, int out_size, void* d_ws, size_t ws_size,
                              hipStream_t stream) {
    const float* x = (const float*)d_in[0];
    const int* edges = (const int*)d_in[1];
    const int* src = edges;
    const int* dst = edges + N_EDGES;
    const float* Wl[3] = {(const float*)d_in[2], (const float*)d_in[7],  (const float*)d_in[12]};
    const float* bl[3] = {(const float*)d_in[3], (const float*)d_in[8],  (const float*)d_in[13]};
    const float* Wr[3] = {(const float*)d_in[4], (const float*)d_in[9],  (const float*)d_in[14]};
    const float* g[3]  = {(const float*)d_in[5], (const float*)d_in[10], (const float*)d_in[15]};
    const float* b[3]  = {(const float*)d_in[6], (const float*)d_in[11], (const float*)d_in[16]};

    char* ws = (char*)d_ws;
    int* s_src = (int*)(ws + OFF_SSRC);
    int* offs  = (int*)(ws + OFF_OFFS);
    unsigned short* wpack = (unsigned short*)(ws + OFF_CURS);
    int* gcur  = (int*)(ws + OFF_BSUM);
    int* bbase = (int*)(ws + OFF_BSUM + 2048);
    float* M = (float*)(ws + OFF_M);
    uint2* staging = (uint2*)(ws + OFF_M);     // aliases M; dead before first agg
    unsigned short* Xhi = (unsigned short*)(ws + OFF_XHI);
    unsigned short* Xlo = (unsigned short*)(ws + OFF_XLO);
    float* out = (float*)d_out;

    // ---- locality-preserving bucket sort of edges by dst ----
    hipMemsetAsync(gcur, 0, NB * sizeof(int), stream);
    part_kernel<<<(N_EDGES + 4095) / 4096, 256, 0, stream>>>(src, dst, gcur, staging);
    bscan_kernel<<<1, 512, 0, stream>>>(gcur, bbase, offs);
    bsort_kernel<<<NB, 256, 0, stream>>>(staging, gcur, bbase, offs, s_src);
    // weights -> bf16 hi/lo fragments; x -> bf16 hi/lo planes
    pack_kernel<<<(3 * 32768) / 256, 256, 0, stream>>>(Wl[0], Wr[0], Wl[1], Wr[1], Wl[2], Wr[2], wpack);
    cvt_kernel<<<(N_NODES * 64) / 256, 256, 0, stream>>>(x, (unsigned int*)Xhi, (unsigned int*)Xlo);

    const int MMB = (N_NODES + 127) / 128;  // 782
    unsigned short* ph[3] = {wpack, wpack + 65536, wpack + 131072};

    // ---- layer 0 ----
    agg_kernel<<<N_NODES / 4, 256, 0, stream>>>((const unsigned int*)Xhi, s_src, offs, M);
    mmln_kernel<<<MMB, 256, 0, stream>>>(Xhi, Xlo, M, ph[0], ph[0] + 32768, bl[0], g[0], b[0], nullptr, 0);
    // ---- layer 1 ----
    agg_kernel<<<N_NODES / 4, 256, 0, stream>>>((const unsigned int*)Xhi, s_src, offs, M);
    mmln_kernel<<<MMB, 256, 0, stream>>>(Xhi, Xlo, M, ph[1], ph[1] + 32768, bl[1], g[1], b[1], nullptr, 0);
    // ---- layer 2 ----
    agg_kernel<<<N_NODES / 4, 256, 0, stream>>>((const unsigned int*)Xhi, s_src, offs, M);
    mmln_kernel<<<MMB, 256, 0, stream>>>(Xhi, Xlo, M, ph[2], ph[2] + 32768, bl[2], g[2], b[2], out, 1);
}